// Round 10
// baseline (370.107 us; speedup 1.0000x reference)
//
#include <hip/hip_runtime.h>

#define NBATCH 8
#define NN     207
#define DHID   256
#define LL     2484      // 12*207
#define LLP    2496      // padded to multiple of 32
#define RT     32        // query rows per block
#define TILES  78        // LLP/32
#define TPW    10        // j-tiles per wave (8 waves, 8*10 >= 78)
#define LNEPS  1e-5f

typedef __attribute__((ext_vector_type(8)))  short bf16x8;
typedef __attribute__((ext_vector_type(4)))  unsigned u32x4;
typedef __attribute__((ext_vector_type(16))) float f32x16;

__device__ __forceinline__ short f2bf(float f) {
    unsigned u = __float_as_uint(f);
    unsigned r = (u + 0x7FFFu + ((u >> 16) & 1u)) >> 16;
    return (short)r;
}
__device__ __forceinline__ unsigned cvt_pk_bf16(float lo, float hi) {
    unsigned r;
    asm("v_cvt_pk_bf16_f32 %0, %1, %2" : "=v"(r) : "v"(lo), "v"(hi));
    return r;
}
__device__ __forceinline__ void pl32swap(unsigned& a, unsigned& b) {
    asm("v_permlane32_swap_b32 %0, %1" : "+v"(a), "+v"(b));
}
// shared score quantizer: MUST be bitwise identical between k_score and k_pv
__device__ __forceinline__ int score_g(float c, float sv) {
    float sg = 1.0f / (1.0f + __expf(c * -0.125f));
    float s = sg * sv;
    int g = (int)(s * 65536.0f);
    return (g > 65535) ? 65535 : g;
}

// ---------------- Kernel 1: LayerNorm + Q/K projections ----------------
__global__ __launch_bounds__(256) void k_lnproj(
    const float* __restrict__ x, const float* __restrict__ Wq, const float* __restrict__ bq,
    const float* __restrict__ Wk, const float* __restrict__ bk,
    const float* __restrict__ gamma, const float* __restrict__ beta,
    float* __restrict__ Xn, float* __restrict__ Qb, short* __restrict__ Kbf)
{
    __shared__ float xrow[4][64];
    int w = threadIdx.x >> 6, lane = threadIdx.x & 63;
    size_t row = (size_t)blockIdx.x * 4 + w;
    float xv = x[row * 64 + lane];
    float m = xv;
    #pragma unroll
    for (int o = 32; o; o >>= 1) m += __shfl_xor(m, o, 64);
    m *= (1.0f / 64.0f);
    float dv = xv - m;
    float var = dv * dv;
    #pragma unroll
    for (int o = 32; o; o >>= 1) var += __shfl_xor(var, o, 64);
    var *= (1.0f / 64.0f);
    float xg = dv * (1.0f / sqrtf(var + LNEPS)) * gamma[lane] + beta[lane];
    Xn[row * 64 + lane] = xg;
    xrow[w][lane] = xg;
    __syncthreads();
    float q = bq[lane], k = bk[lane];
    #pragma unroll 8
    for (int e = 0; e < 64; e++) {
        float xe = xrow[w][e];
        q += xe * Wq[e * 64 + lane];
        k += xe * Wk[e * 64 + lane];
    }
    int br = (int)(row / LL);
    int jl = (int)(row - (size_t)br * LL);
    Qb[((size_t)br * LLP + jl) * 64 + lane] = q;
    Kbf[((size_t)br * LLP + jl) * 64 + lane] = f2bf(k);
}

// ---------------- Kernel 1b: transpose Xn -> bf16 X^T, zero all pads ----------------
__global__ __launch_bounds__(256) void k_prep(
    const float* __restrict__ Xn, short* __restrict__ XbfT,
    short* __restrict__ Kbf, float* __restrict__ Qb)
{
    __shared__ float tile[64][65];
    int bb = blockIdx.x & 7;
    int jt = blockIdx.x >> 3;          // 0..38
    int j0 = jt * 64;
    for (int i = threadIdx.x; i < 4096; i += 256) {
        int jl = i >> 6, d = i & 63;
        int j = j0 + jl;
        tile[jl][d] = (j < LL) ? Xn[((size_t)bb * LL + j) * 64 + d] : 0.f;
    }
    __syncthreads();
    for (int i = threadIdx.x; i < 4096; i += 256) {
        int d = i >> 6, jl = i & 63;
        XbfT[((size_t)bb * 64 + d) * LLP + j0 + jl] = f2bf(tile[jl][d]);
    }
    if (jt == 38) {
        for (int i = threadIdx.x; i < (LLP - LL) * 64; i += 256) {
            int jl = i >> 6, d = i & 63;
            Kbf[((size_t)bb * LLP + LL + jl) * 64 + d] = 0;
            Qb [((size_t)bb * LLP + LL + jl) * 64 + d] = 0.f;
        }
    }
}

// ---------------- Kernel 2a: swapped-MFMA scores, single-pass 512-bin select ----------------
__global__ __launch_bounds__(512, 4) void k_score(
    const float* __restrict__ Qb, const short* __restrict__ Kbf,
    const float* __restrict__ stg, const int* __restrict__ topk_p,
    unsigned* __restrict__ TG)
{
    __shared__ unsigned hist[RT * 256];     // 512 bins/row, packed 2x u16 per word: 32 KB
    __shared__ int gmax_lds[RT];
    __shared__ unsigned thr_lds[RT];

    int tid = threadIdx.x;
    int lane = tid & 63, wv = tid >> 6;     // wv in [0,8)
    int hi = lane >> 5, l31 = lane & 31;
    int b = blockIdx.x & 7;
    int tile = blockIdx.x >> 3;             // 0..77
    int row0 = tile * RT;

    for (int i = tid; i < RT * 256; i += 512) hist[i] = 0u;
    if (tid < RT) gmax_lds[tid] = 0;

    int keff;
    { int tk = *topk_p; keff = (tk < 5) ? tk * NN : tk; }

    // B-operand: this lane's own query row (padded Qb -> in-bounds, zero on pad)
    bf16x8 qf[4];
    {
        const float* qp = Qb + ((size_t)b * LLP + row0 + l31) * 64 + hi * 8;
        #pragma unroll
        for (int kk = 0; kk < 4; kk++) {
            bf16x8 f;
            #pragma unroll
            for (int e = 0; e < 8; e++) f[e] = f2bf(qp[kk * 16 + e]);
            qf[kk] = f;
        }
    }
    int query = row0 + l31;
    bool rv = (query < LL);
    const float* stgrow = stg + (size_t)b * LL * LL + (size_t)query * LL;
    __syncthreads();   // hist/gmax init visible

    // ---- single sweep: g -> 512-bin hist + gmax ----
    int gmx = 0;
    for (int t = 0; t < TPW; ++t) {
        int ti = wv * TPW + t;
        if (ti < TILES) {
            int j0 = ti * 32;
            int jbA = j0 + 4 * hi;
            int jbB = jbA + 8;
            int jbC = j0 + 16 + 4 * hi;
            int jbD = jbC + 8;
            float4 z4 = make_float4(0.f, 0.f, 0.f, 0.f);
            float4 sA = (rv && jbA < LL) ? *(const float4*)(stgrow + jbA) : z4;
            float4 sB = (rv && jbB < LL) ? *(const float4*)(stgrow + jbB) : z4;
            float4 sC = (rv && jbC < LL) ? *(const float4*)(stgrow + jbC) : z4;
            float4 sD = (rv && jbD < LL) ? *(const float4*)(stgrow + jbD) : z4;
            const short* kbase = Kbf + ((size_t)b * LLP + j0 + l31) * 64 + hi * 8;
            bf16x8 kv0 = *(const bf16x8*)(kbase);
            bf16x8 kv1 = *(const bf16x8*)(kbase + 16);
            bf16x8 kv2 = *(const bf16x8*)(kbase + 32);
            bf16x8 kv3 = *(const bf16x8*)(kbase + 48);
            f32x16 c = {0.f,0.f,0.f,0.f,0.f,0.f,0.f,0.f,0.f,0.f,0.f,0.f,0.f,0.f,0.f,0.f};
            c = __builtin_amdgcn_mfma_f32_32x32x16_bf16(kv0, qf[0], c, 0, 0, 0);
            c = __builtin_amdgcn_mfma_f32_32x32x16_bf16(kv1, qf[1], c, 0, 0, 0);
            c = __builtin_amdgcn_mfma_f32_32x32x16_bf16(kv2, qf[2], c, 0, 0, 0);
            c = __builtin_amdgcn_mfma_f32_32x32x16_bf16(kv3, qf[3], c, 0, 0, 0);
            bool vA = rv && (jbA < LL), vB = rv && (jbB < LL);
            bool vC = rv && (jbC < LL), vD = rv && (jbD < LL);
            float svs[16] = {sA.x, sA.y, sA.z, sA.w, sB.x, sB.y, sB.z, sB.w,
                             sC.x, sC.y, sC.z, sC.w, sD.x, sD.y, sD.z, sD.w};
            #pragma unroll
            for (int r = 0; r < 16; r++) {
                bool v = (r < 4) ? vA : (r < 8) ? vB : (r < 12) ? vC : vD;
                int g = score_g(c[r], svs[r]);
                if (v) {
                    // bin = g>>7 (512 bins); word = bin>>1 = g>>8; half = (g>>7)&1
                    atomicAdd(&hist[l31 * 256 + (g >> 8)], 1u << (((g >> 7) & 1) << 4));
                    gmx = (g > gmx) ? g : gmx;
                }
            }
        }
    }
    {
        int o2 = __shfl_xor(gmx, 32, 64);
        gmx = (o2 > gmx) ? o2 : gmx;
        if (lane < 32) atomicMax(&gmax_lds[l31], gmx);
    }
    __syncthreads();

    // ---- scan: 4 rows per wave, 512 bins (8 per lane) ----
    #pragma unroll 1
    for (int rr = 0; rr < 4; rr++) {
        int row = wv * 4 + rr;
        const unsigned* h = &hist[row * 256];
        unsigned w0 = h[lane * 4 + 0], w1 = h[lane * 4 + 1];
        unsigned w2 = h[lane * 4 + 2], w3 = h[lane * 4 + 3];
        unsigned cb[8] = {w0 & 0xFFFFu, w0 >> 16, w1 & 0xFFFFu, w1 >> 16,
                          w2 & 0xFFFFu, w2 >> 16, w3 & 0xFFFFu, w3 >> 16};
        unsigned S = cb[0] + cb[1] + cb[2] + cb[3] + cb[4] + cb[5] + cb[6] + cb[7];
        unsigned T = S;
        #pragma unroll
        for (int off = 1; off < 64; off <<= 1) {
            unsigned t = __shfl_down(T, off, 64);
            T += (lane + off < 64) ? t : 0u;
        }
        unsigned Tn = T - S;                // suffix starting at lane*8+8
        unsigned sfx[9];
        sfx[8] = Tn;
        #pragma unroll
        for (int i = 7; i >= 0; i--) sfx[i] = cb[i] + sfx[i + 1];
        unsigned kr = (unsigned)keff;
        int hit = -1; unsigned nk = 0, m = 0;
        #pragma unroll
        for (int i = 0; i < 8; i++) {
            if (sfx[i] >= kr && sfx[i + 1] < kr) { hit = i; nk = kr - sfx[i + 1]; m = cb[i]; }
        }
        unsigned long long mask = __ballot(hit >= 0);
        if (mask == 0ull) {
            if (lane == 0) thr_lds[row] = 65535u;   // empty/pad row
        } else {
            int src = __ffsll(mask) - 1;
            int bini = __shfl(hit, src, 64);
            nk = (unsigned)__shfl((int)nk, src, 64);
            m  = (unsigned)__shfl((int)m,  src, 64);
            if (lane == 0) {
                int bin = src * 8 + bini;
                // balanced edge: drop in-bin if that errs less, else keep all in-bin
                int drop = (2u * nk <= m) ? 1 : 0;
                int thrge = bin * 128 + (drop ? 128 : 0);   // keep g >= thrge
                if (thrge > 65535) thrge = 65535;
                thr_lds[row] = (unsigned)thrge;
            }
        }
    }
    __syncthreads();

    if (tid < RT) {
        int grow = row0 + tid;
        unsigned tg = (grow < LL)
            ? (((unsigned)gmax_lds[tid] << 16) | (thr_lds[tid] & 0xFFFFu))
            : 0xFFFFFFFFu;
        TG[(size_t)b * LLP + grow] = tg;
    }
}

// ---------------- Kernel 2b: PV with swapped-QK recompute + permlane pack ----------------
__global__ __launch_bounds__(512, 4) void k_pv(
    const float* __restrict__ Xn, const float* __restrict__ Qb,
    const short* __restrict__ Kbf, const short* __restrict__ XbfT,
    const float* __restrict__ stg, const unsigned* __restrict__ TG,
    float* __restrict__ Z)
{
    __shared__ float red[RT][65];           // 8.3 KB
    __shared__ float rowsum[RT];

    int tid = threadIdx.x;
    int lane = tid & 63, wv = tid >> 6;     // 0..7
    int hi = lane >> 5, l31 = lane & 31;
    int b = blockIdx.x & 7;
    int tile = blockIdx.x >> 3;
    int row0 = tile * RT;

    for (int i = tid; i < RT * 65; i += 512) ((float*)red)[i] = 0.f;
    if (tid < RT) rowsum[tid] = 0.f;

    bf16x8 qf[4];
    {
        const float* qp = Qb + ((size_t)b * LLP + row0 + l31) * 64 + hi * 8;
        #pragma unroll
        for (int kk = 0; kk < 4; kk++) {
            bf16x8 f;
            #pragma unroll
            for (int e = 0; e < 8; e++) f[e] = f2bf(qp[kk * 16 + e]);
            qf[kk] = f;
        }
    }
    unsigned tg = TG[(size_t)b * LLP + row0 + l31];
    int thrge = (int)(tg & 0xFFFFu);
    int gmax = (int)(tg >> 16);
    int query = row0 + l31;
    bool rv = (query < LL);
    const float* stgrow = stg + (size_t)b * LL * LL + (size_t)query * LL;
    const short* xb0 = XbfT + ((size_t)b * 64 + l31) * LLP + hi * 8;
    const short* xb1 = XbfT + ((size_t)b * 64 + 32 + l31) * LLP + hi * 8;

    f32x16 p0 = {0.f,0.f,0.f,0.f,0.f,0.f,0.f,0.f,0.f,0.f,0.f,0.f,0.f,0.f,0.f,0.f};
    f32x16 p1 = p0;
    float smr = 0.f;
    __syncthreads();   // red/rowsum init visible

    for (int t = 0; t < TPW; ++t) {
        int ti = wv * TPW + t;
        if (ti < TILES) {
            int j0 = ti * 32;
            int jbA = j0 + 4 * hi;
            int jbB = jbA + 8;
            int jbC = j0 + 16 + 4 * hi;
            int jbD = jbC + 8;
            float4 z4 = make_float4(0.f, 0.f, 0.f, 0.f);
            float4 sA = (rv && jbA < LL) ? *(const float4*)(stgrow + jbA) : z4;
            float4 sB = (rv && jbB < LL) ? *(const float4*)(stgrow + jbB) : z4;
            float4 sC = (rv && jbC < LL) ? *(const float4*)(stgrow + jbC) : z4;
            float4 sD = (rv && jbD < LL) ? *(const float4*)(stgrow + jbD) : z4;
            const short* kbase = Kbf + ((size_t)b * LLP + j0 + l31) * 64 + hi * 8;
            bf16x8 kv0 = *(const bf16x8*)(kbase);
            bf16x8 kv1 = *(const bf16x8*)(kbase + 16);
            bf16x8 kv2 = *(const bf16x8*)(kbase + 32);
            bf16x8 kv3 = *(const bf16x8*)(kbase + 48);
            f32x16 c = {0.f,0.f,0.f,0.f,0.f,0.f,0.f,0.f,0.f,0.f,0.f,0.f,0.f,0.f,0.f,0.f};
            c = __builtin_amdgcn_mfma_f32_32x32x16_bf16(kv0, qf[0], c, 0, 0, 0);
            c = __builtin_amdgcn_mfma_f32_32x32x16_bf16(kv1, qf[1], c, 0, 0, 0);
            c = __builtin_amdgcn_mfma_f32_32x32x16_bf16(kv2, qf[2], c, 0, 0, 0);
            c = __builtin_amdgcn_mfma_f32_32x32x16_bf16(kv3, qf[3], c, 0, 0, 0);
            float svs[16] = {sA.x, sA.y, sA.z, sA.w, sB.x, sB.y, sB.z, sB.w,
                             sC.x, sC.y, sC.z, sC.w, sD.x, sD.y, sD.z, sD.w};
            #pragma unroll
            for (int grp = 0; grp < 2; grp++) {
                float ev[8];
                #pragma unroll
                for (int r = 0; r < 8; r++) {
                    int reg = grp * 8 + r;
                    int g = score_g(c[reg], svs[reg]);
                    bool keep = (g >= thrge) || (g == gmax && g > 0);
                    ev[r] = keep ? __expf((float)(g - gmax) * (1.0f / 65536.0f)) : 0.f;
                    smr += ev[r];
                }
                unsigned a0 = cvt_pk_bf16(ev[0], ev[1]);
                unsigned a1 = cvt_pk_bf16(ev[2], ev[3]);
                unsigned c0 = cvt_pk_bf16(ev[4], ev[5]);
                unsigned c1 = cvt_pk_bf16(ev[6], ev[7]);
                pl32swap(a0, c0);
                pl32swap(a1, c1);
                u32x4 w; w[0] = a0; w[1] = a1; w[2] = c0; w[3] = c1;
                bf16x8 ea = __builtin_bit_cast(bf16x8, w);
                bf16x8 x0 = *(const bf16x8*)(xb0 + j0 + grp * 16);
                bf16x8 x1 = *(const bf16x8*)(xb1 + j0 + grp * 16);
                p0 = __builtin_amdgcn_mfma_f32_32x32x16_bf16(ea, x0, p0, 0, 0, 0);
                p1 = __builtin_amdgcn_mfma_f32_32x32x16_bf16(ea, x1, p1, 0, 0, 0);
            }
        }
    }
    smr += __shfl_xor(smr, 32, 64);
    if (lane < 32) atomicAdd(&rowsum[l31], smr);
    #pragma unroll
    for (int reg = 0; reg < 16; reg++) {
        int row = (reg & 3) + 8 * (reg >> 2) + 4 * hi;
        atomicAdd(&red[row][l31],      p0[reg]);
        atomicAdd(&red[row][32 + l31], p1[reg]);
    }
    __syncthreads();

    for (int i = tid; i < RT * 64; i += 512) {
        int r = i >> 6, d = i & 63;
        int grow = row0 + r;
        if (grow < LL) {
            size_t gi = ((size_t)b * LL + grow) * 64 + d;
            Z[gi] = red[r][d] * (1.0f / rowsum[r]) + Xn[gi];
        }
    }
}

// ---------------- Kernel 3: fused LN + FFN + residual ----------------
__global__ __launch_bounds__(256) void k_ffn(
    const float* __restrict__ Zb, const float* __restrict__ fg, const float* __restrict__ fb,
    const float* __restrict__ w1, const float* __restrict__ b1,
    const float* __restrict__ w2, const float* __restrict__ b2,
    float* __restrict__ out)
{
    const int G2 = 16;
    __shared__ float zr[G2][64];
    __shared__ float zl[G2][64];
    __shared__ float h[G2][DHID];
    int tid = threadIdx.x;
    int w = tid >> 6, lane = tid & 63;
    size_t row0 = (size_t)blockIdx.x * G2;
    for (int rr = w; rr < G2; rr += 4) {
        float zv = Zb[(row0 + rr) * 64 + lane];
        zr[rr][lane] = zv;
        float m = zv;
        #pragma unroll
        for (int o = 32; o; o >>= 1) m += __shfl_xor(m, o, 64);
        m *= (1.0f / 64.0f);
        float dv = zv - m;
        float var = dv * dv;
        #pragma unroll
        for (int o = 32; o; o >>= 1) var += __shfl_xor(var, o, 64);
        var *= (1.0f / 64.0f);
        zl[rr][lane] = dv * (1.0f / sqrtf(var + LNEPS)) * fg[lane] + fb[lane];
    }
    __syncthreads();
    float hacc[G2];
    #pragma unroll
    for (int g = 0; g < G2; g++) hacc[g] = 0.f;
    for (int d = 0; d < 64; d++) {
        float wv1 = w1[d * DHID + tid];
        #pragma unroll
        for (int g = 0; g < G2; g++) hacc[g] += zl[g][d] * wv1;
    }
    float b1v = b1[tid];
    #pragma unroll
    for (int g = 0; g < G2; g++) h[g][tid] = fmaxf(hacc[g] + b1v, 0.f);
    __syncthreads();
    float oacc[4] = {0.f, 0.f, 0.f, 0.f};
    for (int i = 0; i < DHID; i++) {
        float wv2 = w2[i * 64 + lane];
        #pragma unroll
        for (int rr = 0; rr < 4; rr++) oacc[rr] += h[w * 4 + rr][i] * wv2;
    }
    float b2v = b2[lane];
    #pragma unroll
    for (int rr = 0; rr < 4; rr++)
        out[(row0 + w * 4 + rr) * 64 + lane] = zr[w * 4 + rr][lane] + oacc[rr] + b2v;
}

extern "C" void kernel_launch(void* const* d_in, const int* in_sizes, int n_in,
                              void* d_out, int out_size, void* d_ws, size_t ws_size,
                              hipStream_t stream)
{
    const float* x      = (const float*)d_in[0];
    const float* stg    = (const float*)d_in[1];
    const float* Wq     = (const float*)d_in[2];
    const float* bq     = (const float*)d_in[3];
    const float* Wk     = (const float*)d_in[4];
    const float* bk     = (const float*)d_in[5];
    const float* gamma  = (const float*)d_in[6];
    const float* beta   = (const float*)d_in[7];
    const float* fgamma = (const float*)d_in[8];
    const float* fbeta  = (const float*)d_in[9];
    const float* w1     = (const float*)d_in[10];
    const float* b1     = (const float*)d_in[11];
    const float* w2     = (const float*)d_in[12];
    const float* b2     = (const float*)d_in[13];
    const int*   topk   = (const int*)d_in[14];
    float* out = (float*)d_out;

    const size_t rows  = (size_t)NBATCH * LL;    // 19872
    const size_t prows = (size_t)NBATCH * LLP;   // 19968
    float* Xn = (float*)d_ws;                    // rows*64 f32
    float* Qb = Xn + rows * 64;                  // prows*64 f32 (padded)
    float* Z  = Qb + prows * 64;                 // rows*64 f32
    short* Kbf  = (short*)(Z + rows * 64);       // prows*64 bf16
    short* XbfT = Kbf + prows * 64;              // prows*64 bf16 (transposed layout)
    unsigned* TG = (unsigned*)(XbfT + prows * 64); // prows u32
    // total ~20.5 MB — proven ws budget

    k_lnproj<<<(int)(rows / 4), 256, 0, stream>>>(x, Wq, bq, Wk, bk, gamma, beta, Xn, Qb, Kbf);
    k_prep<<<NBATCH * 39, 256, 0, stream>>>(Xn, XbfT, Kbf, Qb);
    k_score<<<NBATCH * TILES, 512, 0, stream>>>(Qb, Kbf, stg, topk, TG);
    k_pv<<<NBATCH * TILES, 512, 0, stream>>>(Xn, Qb, Kbf, XbfT, stg, TG, Z);
    k_ffn<<<(int)(rows / 16), 256, 0, stream>>>(Z, fgamma, fbeta, w1, b1, w2, b2, out);
}

// Round 11
// 319.284 us; speedup vs baseline: 1.1592x; 1.1592x over previous
//
#include <hip/hip_runtime.h>

#define NBATCH 8
#define NN     207
#define DHID   256
#define LL     2484      // 12*207
#define LLP    2496      // padded to multiple of 32
#define RT     26        // query rows per block (96 blocks/batch: 96*26=2496)
#define NBLK   96
#define GCOL   2560      // G-tile padded cols (multiple of 128 for swizzle)
#define TILES  78        // LLP/32
#define SENT   0xFFFFu
#define LNEPS  1e-5f

typedef __attribute__((ext_vector_type(8)))  short bf16x8;
typedef __attribute__((ext_vector_type(8)))  unsigned short u16x8;
typedef __attribute__((ext_vector_type(16))) float f32x16;

__device__ __forceinline__ short f2bf(float f) {
    unsigned u = __float_as_uint(f);
    unsigned r = (u + 0x7FFFu + ((u >> 16) & 1u)) >> 16;
    return (short)r;
}

// ---------------- Kernel 1: LayerNorm + Q/K projections ----------------
__global__ __launch_bounds__(256) void k_lnproj(
    const float* __restrict__ x, const float* __restrict__ Wq, const float* __restrict__ bq,
    const float* __restrict__ Wk, const float* __restrict__ bk,
    const float* __restrict__ gamma, const float* __restrict__ beta,
    float* __restrict__ Xn, float* __restrict__ Qb, short* __restrict__ Kbf)
{
    __shared__ float xrow[4][64];
    int w = threadIdx.x >> 6, lane = threadIdx.x & 63;
    size_t row = (size_t)blockIdx.x * 4 + w;
    float xv = x[row * 64 + lane];
    float m = xv;
    #pragma unroll
    for (int o = 32; o; o >>= 1) m += __shfl_xor(m, o, 64);
    m *= (1.0f / 64.0f);
    float dv = xv - m;
    float var = dv * dv;
    #pragma unroll
    for (int o = 32; o; o >>= 1) var += __shfl_xor(var, o, 64);
    var *= (1.0f / 64.0f);
    float xg = dv * (1.0f / sqrtf(var + LNEPS)) * gamma[lane] + beta[lane];
    Xn[row * 64 + lane] = xg;
    xrow[w][lane] = xg;
    __syncthreads();
    float q = bq[lane], k = bk[lane];
    #pragma unroll 8
    for (int e = 0; e < 64; e++) {
        float xe = xrow[w][e];
        q += xe * Wq[e * 64 + lane];
        k += xe * Wk[e * 64 + lane];
    }
    int br = (int)(row / LL);
    int jl = (int)(row - (size_t)br * LL);
    Qb[((size_t)br * LLP + jl) * 64 + lane] = q;
    Kbf[((size_t)br * LLP + jl) * 64 + lane] = f2bf(k);
}

// ---------------- Kernel 1b: transpose Xn -> bf16 X^T, zero all pads ----------------
__global__ __launch_bounds__(256) void k_prep(
    const float* __restrict__ Xn, short* __restrict__ XbfT,
    short* __restrict__ Kbf, float* __restrict__ Qb)
{
    __shared__ float tile[64][65];
    int bb = blockIdx.x & 7;
    int jt = blockIdx.x >> 3;          // 0..38
    int j0 = jt * 64;
    for (int i = threadIdx.x; i < 4096; i += 256) {
        int jl = i >> 6, d = i & 63;
        int j = j0 + jl;
        tile[jl][d] = (j < LL) ? Xn[((size_t)bb * LL + j) * 64 + d] : 0.f;
    }
    __syncthreads();
    for (int i = threadIdx.x; i < 4096; i += 256) {
        int d = i >> 6, jl = i & 63;
        XbfT[((size_t)bb * 64 + d) * LLP + j0 + jl] = f2bf(tile[jl][d]);
    }
    if (jt == 38) {
        for (int i = threadIdx.x; i < (LLP - LL) * 64; i += 256) {
            int jl = i >> 6, d = i & 63;
            Kbf[((size_t)bb * LLP + LL + jl) * 64 + d] = 0;
            Qb [((size_t)bb * LLP + LL + jl) * 64 + d] = 0.f;
        }
    }
}

// ---------------- Kernel 2: fully fused attn, one coalesced stg pass, G in LDS ----------------
__global__ __launch_bounds__(1024, 4) void k_attn(
    const float* __restrict__ Xn, const float* __restrict__ Qb,
    const short* __restrict__ Kbf, const short* __restrict__ XbfT,
    const float* __restrict__ stg, const int* __restrict__ topk_p,
    float* __restrict__ Z)
{
    __shared__ __align__(16) unsigned short Gt[RT * GCOL];   // 133,120 B
    __shared__ __align__(16) unsigned hist[RT * 256];        // 26,624 B (512-bin packed u16x2)
    __shared__ int gmax_lds[RT];
    __shared__ unsigned thr_lds[RT];
    float* redf = (float*)hist;            // union: red[RT*65] + rowsum[RT], hist dead after scan
    float* rowsum = redf + RT * 65;

    int tid = threadIdx.x;
    int lane = tid & 63, wv = tid >> 6;    // wv in [0,16)
    int hi = lane >> 5, l31 = lane & 31;
    int b = blockIdx.x & 7;
    int tile = blockIdx.x >> 3;            // 0..95
    int row0 = tile * RT;

    // ---- init: Gt = sentinel, hist = 0, gmax = 0 ----
    for (int i = tid; i < RT * GCOL / 2; i += 1024) ((unsigned*)Gt)[i] = 0xFFFFFFFFu;
    for (int i = tid; i < RT * 256; i += 1024) hist[i] = 0u;
    if (tid < RT) gmax_lds[tid] = 0;

    int keff;
    { int tk = *topk_p; keff = (tk < 5) ? tk * NN : tk; }

    // Q A-fragments: row = row0 + l31 (rows >= RT give garbage -> discarded downstream)
    bf16x8 qf[4];
    {
        const float* qp = Qb + ((size_t)b * LLP + row0 + l31) * 64 + hi * 8;
        #pragma unroll
        for (int kk = 0; kk < 4; kk++) {
            bf16x8 f;
            #pragma unroll
            for (int e = 0; e < 8; e++) f[e] = f2bf(qp[kk * 16 + e]);
            qf[kk] = f;
        }
    }
    const float* stgb = stg + (size_t)b * LL * LL;
    int kt0 = wv * 5;
    int kt1 = (kt0 + 5 < TILES) ? kt0 + 5 : TILES;
    __syncthreads();   // init visible

    // ---- Phase A: coalesced stg + MFMA scores -> u16 g in LDS + hist + gmax ----
    int gmx[16];
    #pragma unroll
    for (int i = 0; i < 16; i++) gmx[i] = 0;
    for (int kt = kt0; kt < kt1; ++kt) {
        int j0 = kt * 32;
        int j = j0 + l31;
        bool vj = (j < LL);
        // issue all 16 coalesced stg loads up front
        float svs[16];
        #pragma unroll
        for (int reg = 0; reg < 16; reg++) {
            int trow = (reg & 3) + 8 * (reg >> 2) + 4 * hi;
            int grow = row0 + trow;
            bool v = vj && (trow < RT) && (grow < LL);
            svs[reg] = v ? stgb[(size_t)grow * LL + j] : 0.f;
        }
        const short* kbase = Kbf + ((size_t)b * LLP + j) * 64 + hi * 8;
        bf16x8 kv0 = *(const bf16x8*)(kbase);
        bf16x8 kv1 = *(const bf16x8*)(kbase + 16);
        bf16x8 kv2 = *(const bf16x8*)(kbase + 32);
        bf16x8 kv3 = *(const bf16x8*)(kbase + 48);
        f32x16 c = {0.f,0.f,0.f,0.f,0.f,0.f,0.f,0.f,0.f,0.f,0.f,0.f,0.f,0.f,0.f,0.f};
        c = __builtin_amdgcn_mfma_f32_32x32x16_bf16(qf[0], kv0, c, 0, 0, 0);
        c = __builtin_amdgcn_mfma_f32_32x32x16_bf16(qf[1], kv1, c, 0, 0, 0);
        c = __builtin_amdgcn_mfma_f32_32x32x16_bf16(qf[2], kv2, c, 0, 0, 0);
        c = __builtin_amdgcn_mfma_f32_32x32x16_bf16(qf[3], kv3, c, 0, 0, 0);
        #pragma unroll
        for (int reg = 0; reg < 16; reg++) {
            int trow = (reg & 3) + 8 * (reg >> 2) + 4 * hi;
            int grow = row0 + trow;
            bool v = vj && (trow < RT) && (grow < LL);
            float sg = 1.0f / (1.0f + __expf(c[reg] * -0.125f));
            float s = sg * svs[reg];
            int g = (int)(s * 65536.0f); g = (g > 65534) ? 65534 : g;
            if (v) {
                unsigned col = (unsigned)j ^ ((unsigned)(trow & 15) << 3);
                Gt[trow * GCOL + col] = (unsigned short)g;
                atomicAdd(&hist[trow * 256 + (g >> 8)], 1u << (((g >> 7) & 1) << 4));
                gmx[reg] = (g > gmx[reg]) ? g : gmx[reg];
            }
        }
    }
    #pragma unroll
    for (int reg = 0; reg < 16; reg++) {
        int v = gmx[reg];
        #pragma unroll
        for (int off = 1; off < 32; off <<= 1) {
            int o2 = __shfl_xor(v, off, 64);
            v = (o2 > v) ? o2 : v;
        }
        if (l31 == 0) {
            int trow = (reg & 3) + 8 * (reg >> 2) + 4 * hi;
            if (trow < RT) atomicMax(&gmax_lds[trow], v);
        }
    }
    __syncthreads();   // Gt + hist + gmax complete

    // ---- Phase B: 512-bin scan per row -> threshold (keep g >= thrge) ----
    #pragma unroll 1
    for (int row = wv; row < RT; row += 16) {
        const unsigned* h = &hist[row * 256];
        unsigned w0 = h[lane * 4 + 0], w1 = h[lane * 4 + 1];
        unsigned w2 = h[lane * 4 + 2], w3 = h[lane * 4 + 3];
        unsigned cb[8] = {w0 & 0xFFFFu, w0 >> 16, w1 & 0xFFFFu, w1 >> 16,
                          w2 & 0xFFFFu, w2 >> 16, w3 & 0xFFFFu, w3 >> 16};
        unsigned S = cb[0] + cb[1] + cb[2] + cb[3] + cb[4] + cb[5] + cb[6] + cb[7];
        unsigned T = S;
        #pragma unroll
        for (int off = 1; off < 64; off <<= 1) {
            unsigned t = __shfl_down(T, off, 64);
            T += (lane + off < 64) ? t : 0u;
        }
        unsigned Tn = T - S;
        unsigned sfx[9];
        sfx[8] = Tn;
        #pragma unroll
        for (int i = 7; i >= 0; i--) sfx[i] = cb[i] + sfx[i + 1];
        unsigned kr = (unsigned)keff;
        int hit = -1; unsigned nk = 0, mm = 0;
        #pragma unroll
        for (int i = 0; i < 8; i++) {
            if (sfx[i] >= kr && sfx[i + 1] < kr) { hit = i; nk = kr - sfx[i + 1]; mm = cb[i]; }
        }
        unsigned long long mask = __ballot(hit >= 0);
        if (mask == 0ull) {
            if (lane == 0) thr_lds[row] = 65535u;
        } else {
            int src = __ffsll(mask) - 1;
            int bini = __shfl(hit, src, 64);
            nk = (unsigned)__shfl((int)nk, src, 64);
            mm = (unsigned)__shfl((int)mm, src, 64);
            if (lane == 0) {
                int bin = src * 8 + bini;
                int drop = (2u * nk <= mm) ? 1 : 0;
                int thrge = bin * 128 + (drop ? 128 : 0);
                if (thrge > 65535) thrge = 65535;
                thr_lds[row] = (unsigned)thrge;
            }
        }
    }
    __syncthreads();   // scans done reading hist

    // ---- re-purpose hist region as PV accumulators ----
    for (int i = tid; i < RT * 65 + RT; i += 1024) redf[i] = 0.f;
    __syncthreads();

    // ---- Phase C: PV from LDS G-tile ----
    int arow = l31;
    int agmax = (arow < RT) ? gmax_lds[arow] : 0;
    unsigned athr = (arow < RT) ? thr_lds[arow] : 65535u;
    unsigned swz = ((unsigned)(arow & 15)) << 3;
    const unsigned short* gp = &Gt[arow * GCOL];
    const short* xb0 = XbfT + ((size_t)b * 64 + l31) * LLP + hi * 8;
    const short* xb1 = XbfT + ((size_t)b * 64 + 32 + l31) * LLP + hi * 8;
    f32x16 p0 = {0.f,0.f,0.f,0.f,0.f,0.f,0.f,0.f,0.f,0.f,0.f,0.f,0.f,0.f,0.f,0.f};
    f32x16 p1 = p0;
    float smr = 0.f;
    for (int kt = kt0; kt < kt1; ++kt) {
        int j0 = kt * 32;
        bf16x8 ea[2];
        #pragma unroll
        for (int kk = 0; kk < 2; kk++) {
            unsigned colb = (unsigned)(j0 + kk * 16 + hi * 8) ^ swz;
            u16x8 gv = *(const u16x8*)&gp[colb];
            bf16x8 f;
            #pragma unroll
            for (int e = 0; e < 8; e++) {
                unsigned g = gv[e];
                bool keep = (g != SENT) && (g >= athr || (int)g == agmax);
                float ev = keep ? __expf((float)((int)g - agmax) * (1.0f / 65536.0f)) : 0.f;
                smr += ev;
                f[e] = f2bf(ev);
            }
            ea[kk] = f;
        }
        bf16x8 x00 = *(const bf16x8*)(xb0 + j0);
        bf16x8 x01 = *(const bf16x8*)(xb0 + j0 + 16);
        bf16x8 x10 = *(const bf16x8*)(xb1 + j0);
        bf16x8 x11 = *(const bf16x8*)(xb1 + j0 + 16);
        p0 = __builtin_amdgcn_mfma_f32_32x32x16_bf16(ea[0], x00, p0, 0, 0, 0);
        p0 = __builtin_amdgcn_mfma_f32_32x32x16_bf16(ea[1], x01, p0, 0, 0, 0);
        p1 = __builtin_amdgcn_mfma_f32_32x32x16_bf16(ea[0], x10, p1, 0, 0, 0);
        p1 = __builtin_amdgcn_mfma_f32_32x32x16_bf16(ea[1], x11, p1, 0, 0, 0);
    }
    smr += __shfl_xor(smr, 32, 64);
    if (lane < 32 && l31 < RT) atomicAdd(&rowsum[l31], smr);
    #pragma unroll
    for (int reg = 0; reg < 16; reg++) {
        int trow = (reg & 3) + 8 * (reg >> 2) + 4 * hi;
        if (trow < RT) {
            atomicAdd(&redf[trow * 65 + l31],      p0[reg]);
            atomicAdd(&redf[trow * 65 + 32 + l31], p1[reg]);
        }
    }
    __syncthreads();

    // ---- epilogue: normalize + residual ----
    for (int i = tid; i < RT * 64; i += 1024) {
        int r = i >> 6, d = i & 63;
        int grow = row0 + r;
        if (grow < LL) {
            size_t gi = ((size_t)b * LL + grow) * 64 + d;
            Z[gi] = redf[r * 65 + d] * (1.0f / rowsum[r]) + Xn[gi];
        }
    }
}

// ---------------- Kernel 3: fused LN + FFN + residual ----------------
__global__ __launch_bounds__(256) void k_ffn(
    const float* __restrict__ Zb, const float* __restrict__ fg, const float* __restrict__ fb,
    const float* __restrict__ w1, const float* __restrict__ b1,
    const float* __restrict__ w2, const float* __restrict__ b2,
    float* __restrict__ out)
{
    const int G2 = 16;
    __shared__ float zr[G2][64];
    __shared__ float zl[G2][64];
    __shared__ float h[G2][DHID];
    int tid = threadIdx.x;
    int w = tid >> 6, lane = tid & 63;
    size_t row0 = (size_t)blockIdx.x * G2;
    for (int rr = w; rr < G2; rr += 4) {
        float zv = Zb[(row0 + rr) * 64 + lane];
        zr[rr][lane] = zv;
        float m = zv;
        #pragma unroll
        for (int o = 32; o; o >>= 1) m += __shfl_xor(m, o, 64);
        m *= (1.0f / 64.0f);
        float dv = zv - m;
        float var = dv * dv;
        #pragma unroll
        for (int o = 32; o; o >>= 1) var += __shfl_xor(var, o, 64);
        var *= (1.0f / 64.0f);
        zl[rr][lane] = dv * (1.0f / sqrtf(var + LNEPS)) * fg[lane] + fb[lane];
    }
    __syncthreads();
    float hacc[G2];
    #pragma unroll
    for (int g = 0; g < G2; g++) hacc[g] = 0.f;
    for (int d = 0; d < 64; d++) {
        float wv1 = w1[d * DHID + tid];
        #pragma unroll
        for (int g = 0; g < G2; g++) hacc[g] += zl[g][d] * wv1;
    }
    float b1v = b1[tid];
    #pragma unroll
    for (int g = 0; g < G2; g++) h[g][tid] = fmaxf(hacc[g] + b1v, 0.f);
    __syncthreads();
    float oacc[4] = {0.f, 0.f, 0.f, 0.f};
    for (int i = 0; i < DHID; i++) {
        float wv2 = w2[i * 64 + lane];
        #pragma unroll
        for (int rr = 0; rr < 4; rr++) oacc[rr] += h[w * 4 + rr][i] * wv2;
    }
    float b2v = b2[lane];
    #pragma unroll
    for (int rr = 0; rr < 4; rr++)
        out[(row0 + w * 4 + rr) * 64 + lane] = zr[w * 4 + rr][lane] + oacc[rr] + b2v;
}

extern "C" void kernel_launch(void* const* d_in, const int* in_sizes, int n_in,
                              void* d_out, int out_size, void* d_ws, size_t ws_size,
                              hipStream_t stream)
{
    const float* x      = (const float*)d_in[0];
    const float* stg    = (const float*)d_in[1];
    const float* Wq     = (const float*)d_in[2];
    const float* bq     = (const float*)d_in[3];
    const float* Wk     = (const float*)d_in[4];
    const float* bk     = (const float*)d_in[5];
    const float* gamma  = (const float*)d_in[6];
    const float* beta   = (const float*)d_in[7];
    const float* fgamma = (const float*)d_in[8];
    const float* fbeta  = (const float*)d_in[9];
    const float* w1     = (const float*)d_in[10];
    const float* b1     = (const float*)d_in[11];
    const float* w2     = (const float*)d_in[12];
    const float* b2     = (const float*)d_in[13];
    const int*   topk   = (const int*)d_in[14];
    float* out = (float*)d_out;

    const size_t rows  = (size_t)NBATCH * LL;    // 19872
    const size_t prows = (size_t)NBATCH * LLP;   // 19968
    float* Xn = (float*)d_ws;                    // rows*64 f32
    float* Qb = Xn + rows * 64;                  // (prows+64)*64 f32 (padded + tile-overrun slack)
    float* Z  = Qb + (prows + 64) * 64;          // rows*64 f32
    short* Kbf  = (short*)(Z + rows * 64);       // prows*64 bf16
    short* XbfT = Kbf + prows * 64;              // prows*64 bf16 (transposed layout)
    // total ~20.4 MB — proven ws budget

    k_lnproj<<<(int)(rows / 4), 256, 0, stream>>>(x, Wq, bq, Wk, bk, gamma, beta, Xn, Qb, Kbf);
    k_prep<<<NBATCH * 39, 256, 0, stream>>>(Xn, XbfT, Kbf, Qb);
    k_attn<<<NBATCH * NBLK, 1024, 0, stream>>>(Xn, Qb, Kbf, XbfT, stg, topk, Z);
    k_ffn<<<(int)(rows / 16), 256, 0, stream>>>(Z, fgamma, fbeta, w1, b1, w2, b2, out);
}